// Round 1
// baseline (507.781 us; speedup 1.0000x reference)
//
#include <hip/hip_runtime.h>

// Problem dims
constexpr int NS   = 16;    // batch
constexpr int DIM  = 32;    // in_dim == out_dim
constexpr int FEA  = 192;   // in_f == out_f
constexpr int ELEMS = DIM * FEA;   // 6144 per sample

// epass tiling
constexpr int SPLIT   = 4;              // f-splits per o
constexpr int FPB     = FEA / SPLIT;    // 48 f per block
constexpr int FCHUNK  = 16;             // f per LDS stage
constexpr int NCHUNKS = FPB / FCHUNK;   // 3
constexpr int ROWPAD  = 20;             // 16 floats (n) + 4 pad
constexpr int TPB     = 256;            // epass threads per block: tid = i*8 + dq
constexpr int FSTRIDE = FEA * DIM;      // advance one f in W (6144 floats)
constexpr int PREF    = 4;              // W rolling prefetch depth
constexpr int REDPAD  = 68;             // reduction row stride (64 + 4 pad)
constexpr int SITER   = (FCHUNK * DIM * NS / 4) / TPB;  // 8 float4 stages/thread

__device__ __forceinline__ void fma4(float4& a, float x, const float4& t) {
    a.x = fmaf(x, t.x, a.x);
    a.y = fmaf(x, t.y, a.y);
    a.z = fmaf(x, t.z, a.z);
    a.w = fmaf(x, t.w, a.w);
}

// One FCHUNK of the inner loop. t[PREF]: rolling 4-deep W prefetch.
// LAST suppresses the final PREF loads (would run past W's end).
// Each thread: its own (i, dq), ALL 16 n -> acc[16] float4 (n major, 4 d comps).
template <bool DUAL, bool LAST>
__device__ __forceinline__ void chunk_compute(
    const float* __restrict__ smem, const float* __restrict__ ac0,
    const float* __restrict__ ac1, int i,
    const float*& wp, float4 (&t)[PREF],
    float4* __restrict__ accA, float4* __restrict__ accB)
{
#pragma unroll
    for (int fl = 0; fl < FCHUNK; ++fl) {
        float4 cur = t[fl & (PREF - 1)];
        if (!LAST || fl < FCHUNK - PREF) {       // compile-time after unroll
            t[fl & (PREF - 1)] = *(const float4*)wp;
            wp += FSTRIDE;
        }
        const float a1 = ac0[fl];
        float4 ta = make_float4(cur.x * a1, cur.y * a1, cur.z * a1, cur.w * a1);
        float4 tb;
        if (DUAL) {
            const float a2 = ac1[fl];
            tb = make_float4(cur.x * a2, cur.y * a2, cur.z * a2, cur.w * a2);
        }
        const float* xr = smem + (fl * DIM + i) * ROWPAD;
#pragma unroll
        for (int g = 0; g < 4; ++g) {            // 4 n-groups of 4
            float4 xv = *(const float4*)(xr + g * 4);
            fma4(accA[g * 4 + 0], xv.x, ta);
            fma4(accA[g * 4 + 1], xv.y, ta);
            fma4(accA[g * 4 + 2], xv.z, ta);
            fma4(accA[g * 4 + 3], xv.w, ta);
            if (DUAL) {
                fma4(accB[g * 4 + 0], xv.x, tb);
                fma4(accB[g * 4 + 1], xv.y, tb);
                fma4(accB[g * 4 + 2], xv.z, tb);
                fma4(accB[g * 4 + 3], xv.w, tb);
            }
        }
    }
}

// Weighted contraction:
//   y[n, D, O] = sum_{I=0..31, F} X[n,I,F] * W[I][F][O][D] * A[F][O]
// W layout: [32][192][192][32] (D contiguous)
// X layout: NATURAL [n][I][F] — the stager transposes into LDS [F][I][n].
// Output partials: out[s][O][n*32+D]  (512 floats per (s,O))
// Thread map: tid = i*8 + dq. Each thread: all 16 n x 4 d (dq quad).
// Per wave W load: 8 i x 128B = 1KB fully distinct (no duplicate lanes).
template <bool DUAL>
__global__ __launch_bounds__(TPB) void epass_kernel(
    const float* __restrict__ W, const float* __restrict__ X,
    const float* __restrict__ A1, const float* __restrict__ A2,
    float* __restrict__ outA, float* __restrict__ outB)
{
    __shared__ float smem[FCHUNK * DIM * ROWPAD];  // 10240 floats; reused for reduce
    __shared__ float acol[2][FPB];

    const int tid = threadIdx.x;
    const int o   = blockIdx.x >> 2;          // output O index
    const int s   = blockIdx.x & (SPLIT - 1); // f-split
    const int dq  = tid & 7;                  // D quad (0..7)
    const int i   = tid >> 3;                 // contraction I (0..31)
    const int fBase = s * FPB;

    if (tid < FPB) {
        acol[0][tid] = A1[(fBase + tid) * FEA + o];
        if (DUAL) acol[1][tid] = A2[(fBase + tid) * FEA + o];
    }

    float4 accA[16];
    float4 accB[16];
#pragma unroll
    for (int n = 0; n < 16; ++n) {
        accA[n] = make_float4(0.f, 0.f, 0.f, 0.f);
        if (DUAL) accB[n] = make_float4(0.f, 0.f, 0.f, 0.f);
    }

    const float* wp = W + (size_t)(((i * FEA + fBase) * FEA + o) * DIM + dq * 4);
    float4 t[PREF];
#pragma unroll
    for (int k = 0; k < PREF; ++k) {          // preload fs = 0..3
        t[k] = *(const float4*)wp;
        wp += FSTRIDE;
    }

    for (int c = 0; c < NCHUNKS; ++c) {
        __syncthreads();
        // Stage x chunk from NATURAL layout: 16 f x 32 i x 16 n
#pragma unroll
        for (int r = 0; r < SITER; ++r) {
            int q  = r * TPB + tid;             // 2048 float4 total
            int nn = q >> 7;                    // 0..15
            int ii = (q >> 2) & 31;             // 0..31
            int fq = q & 3;                     // f quad within chunk
            float4 v = *(const float4*)(X + (size_t)(nn * DIM + ii) * FEA
                                          + fBase + c * FCHUNK + fq * 4);
            smem[((fq * 4 + 0) * DIM + ii) * ROWPAD + nn] = v.x;
            smem[((fq * 4 + 1) * DIM + ii) * ROWPAD + nn] = v.y;
            smem[((fq * 4 + 2) * DIM + ii) * ROWPAD + nn] = v.z;
            smem[((fq * 4 + 3) * DIM + ii) * ROWPAD + nn] = v.w;
        }
        __syncthreads();

        const float* ac0 = &acol[0][c * FCHUNK];
        const float* ac1 = &acol[1][c * FCHUNK];
        if (c < NCHUNKS - 1)
            chunk_compute<DUAL, false>(smem, ac0, ac1, i, wp, t, accA, accB);
        else
            chunk_compute<DUAL, true>(smem, ac0, ac1, i, wp, t, accA, accB);
    }

    // Reduce over i. Step 1: fold i_local bit2 (lane bit 5) via shfl.
#pragma unroll
    for (int n = 0; n < 16; ++n) {
        accA[n].x += __shfl_xor(accA[n].x, 32);
        accA[n].y += __shfl_xor(accA[n].y, 32);
        accA[n].z += __shfl_xor(accA[n].z, 32);
        accA[n].w += __shfl_xor(accA[n].w, 32);
        if (DUAL) {
            accB[n].x += __shfl_xor(accB[n].x, 32);
            accB[n].y += __shfl_xor(accB[n].y, 32);
            accB[n].z += __shfl_xor(accB[n].z, 32);
            accB[n].w += __shfl_xor(accB[n].w, 32);
        }
    }

    // Step 2: 16 partial rows (4 waves x 4 i-pairs) x 8 dq -> LDS, then sum.
    const int lane = tid & 63;
    const int wv   = tid >> 6;                               // 0..3
    const int row  = (wv * 4 + ((lane >> 3) & 3)) * 8 + (lane & 7);  // 0..127
    float* red = smem;                                       // reuse staging LDS

    __syncthreads();
    if (!(lane & 32)) {
#pragma unroll
        for (int n = 0; n < 16; ++n)
            *(float4*)&red[row * REDPAD + n * 4] = accA[n];
    }
    __syncthreads();
#pragma unroll
    for (int h = 0; h < 2; ++h) {
        const int e = h * TPB + tid;           // 512 outputs, 2 per thread
        const int n = e >> 5, d = e & 31;
        float v = 0.f;
#pragma unroll
        for (int w2 = 0; w2 < 16; ++w2)
            v += red[(w2 * 8 + (d >> 2)) * REDPAD + n * 4 + (d & 3)];
        outA[(size_t)(s * FEA + o) * (NS * DIM) + e] = v;
    }
    if (DUAL) {
        __syncthreads();
        if (!(lane & 32)) {
#pragma unroll
            for (int n = 0; n < 16; ++n)
                *(float4*)&red[row * REDPAD + n * 4] = accB[n];
        }
        __syncthreads();
#pragma unroll
        for (int h = 0; h < 2; ++h) {
            const int e = h * TPB + tid;
            const int n = e >> 5, d = e & 31;
            float v = 0.f;
#pragma unroll
            for (int w2 = 0; w2 < 16; ++w2)
                v += red[(w2 * 8 + (d >> 2)) * REDPAD + n * 4 + (d & 3)];
            outB[(size_t)(s * FEA + o) * (NS * DIM) + e] = v;
        }
    }
}

// ---- LN helpers (512-thread blocks) --------------------------------------

__device__ __forceinline__ float2 ln_stats_512(float s1, float s2, int tid, float* red) {
#pragma unroll
    for (int m = 1; m < 64; m <<= 1) {
        s1 += __shfl_xor(s1, m);
        s2 += __shfl_xor(s2, m);
    }
    if ((tid & 63) == 0) {
        red[(tid >> 6) * 2]     = s1;
        red[(tid >> 6) * 2 + 1] = s2;
    }
    __syncthreads();
    float a = 0.f, b = 0.f;
#pragma unroll
    for (int ww = 0; ww < 8; ++ww) { a += red[ww * 2]; b += red[ww * 2 + 1]; }
    float mean = a * (1.0f / ELEMS);
    float var  = b * (1.0f / ELEMS) - mean * mean;
    return make_float2(mean, rsqrtf(var + 1e-5f));
}

// h1 = LN(sum_s P). P layout [s][o][n*32+d]; output natural [n][d][o].
__global__ __launch_bounds__(512) void reduce_ln_h1(
    const float* __restrict__ p, float* __restrict__ h1)
{
    __shared__ float vals[FEA * 33];   // [o][d] padded
    __shared__ float red[16];
    const int n = blockIdx.x, tid = threadIdx.x;
    float s1 = 0.f, s2 = 0.f;
    for (int e = tid; e < ELEMS; e += 512) {      // d fast -> coalesced P reads
        int d = e & 31, o = e >> 5;
        float v = 0.f;
#pragma unroll
        for (int sp = 0; sp < SPLIT; ++sp)
            v += p[(size_t)(sp * FEA + o) * (NS * DIM) + n * DIM + d];
        vals[o * 33 + d] = v; s1 += v; s2 += v * v;
    }
    float2 mr = ln_stats_512(s1, s2, tid, red);
    for (int e = tid; e < ELEMS; e += 512) {      // o fast -> coalesced h1 writes
        int o = e % FEA, d = e / FEA;
        h1[(size_t)n * ELEMS + e] = (vals[o * 33 + d] - mr.x) * mr.y;
    }
}

// h2 = LN(0.5*(xs1 + sum_s P)); output natural [n][e][f].
__global__ __launch_bounds__(512) void reduce_ln_h2(
    const float* __restrict__ p, const float* __restrict__ xs1, float* __restrict__ h2)
{
    __shared__ float vals[FEA * 33];
    __shared__ float red[16];
    const int n = blockIdx.x, tid = threadIdx.x;
    for (int e = tid; e < ELEMS; e += 512) {
        int d = e & 31, o = e >> 5;
        float v = 0.f;
#pragma unroll
        for (int sp = 0; sp < SPLIT; ++sp)
            v += p[(size_t)(sp * FEA + o) * (NS * DIM) + n * DIM + d];
        vals[o * 33 + d] = v;
    }
    __syncthreads();
    float s1 = 0.f, s2 = 0.f;
    for (int e = tid; e < ELEMS; e += 512) {      // natural order for xs1
        int o = e % FEA, d = e / FEA;
        float v = 0.5f * (vals[o * 33 + d] + xs1[(size_t)n * ELEMS + e]);
        vals[o * 33 + d] = v; s1 += v; s2 += v * v;
    }
    float2 mr = ln_stats_512(s1, s2, tid, red);
    for (int e = tid; e < ELEMS; e += 512) {
        int o = e % FEA, d = e / FEA;
        h2[(size_t)n * ELEMS + e] = (vals[o * 33 + d] - mr.x) * mr.y;
    }
}

// out = LN((sum_s pB + sum_s pD + h1t1)/3); output natural [n][d][o].
__global__ __launch_bounds__(512) void final_ln(
    const float* __restrict__ pB, const float* __restrict__ pD,
    const float* __restrict__ h1t1, float* __restrict__ out)
{
    __shared__ float vals[FEA * 33];
    __shared__ float red[16];
    const int n = blockIdx.x, tid = threadIdx.x;
    for (int e = tid; e < ELEMS; e += 512) {
        int d = e & 31, o = e >> 5;
        float v = 0.f;
#pragma unroll
        for (int sp = 0; sp < SPLIT; ++sp) {
            v += pB[(size_t)(sp * FEA + o) * (NS * DIM) + n * DIM + d];
            v += pD[(size_t)(sp * FEA + o) * (NS * DIM) + n * DIM + d];
        }
        vals[o * 33 + d] = v;
    }
    __syncthreads();
    float s1 = 0.f, s2 = 0.f;
    for (int e = tid; e < ELEMS; e += 512) {
        int o = e % FEA, d = e / FEA;
        float v = (vals[o * 33 + d] + h1t1[(size_t)n * ELEMS + e]) * (1.0f / 3.0f);
        vals[o * 33 + d] = v; s1 += v; s2 += v * v;
    }
    float2 mr = ln_stats_512(s1, s2, tid, red);
    for (int e = tid; e < ELEMS; e += 512) {
        int o = e % FEA, d = e / FEA;
        out[(size_t)n * ELEMS + e] = (vals[o * 33 + d] - mr.x) * mr.y;
    }
}

// Y[r][j] = sum_f X[r][f] * M[f][j], 8 rows per block, 192 cols
__global__ __launch_bounds__(192) void mm192x8(
    const float* __restrict__ X, const float* __restrict__ M, float* __restrict__ Y)
{
    __shared__ float rows[8][192];
    const int rb = blockIdx.x * 8;
    const int j  = threadIdx.x;
#pragma unroll
    for (int k = 0; k < 8; ++k) rows[k][j] = X[(rb + k) * 192 + j];
    __syncthreads();
    float acc[8] = {0.f, 0.f, 0.f, 0.f, 0.f, 0.f, 0.f, 0.f};
    for (int f = 0; f < 192; ++f) {
        float m = M[f * 192 + j];
#pragma unroll
        for (int k = 0; k < 8; ++k) acc[k] = fmaf(rows[k][f], m, acc[k]);
    }
#pragma unroll
    for (int k = 0; k < 8; ++k) Y[(rb + k) * 192 + j] = acc[k];
}

extern "C" void kernel_launch(void* const* d_in, const int* in_sizes, int n_in,
                              void* d_out, int out_size, void* d_ws, size_t ws_size,
                              hipStream_t stream) {
    (void)in_sizes; (void)n_in; (void)out_size; (void)ws_size;
    const float* x   = (const float*)d_in[0];
    const float* s2t = (const float*)d_in[1];
    const float* t2s = (const float*)d_in[2];
    const float* s0  = (const float*)d_in[3];
    const float* s1  = (const float*)d_in[4];
    /* s2 = d_in[5] unused by the 4-layer schedule */
    const float* t0  = (const float*)d_in[6];
    const float* t1  = (const float*)d_in[7];
    const float* t2  = (const float*)d_in[8];
    float* out = (float*)d_out;

    float* ws = (float*)d_ws;
    float* xs1  = ws; ws += 98304;
    float* h1   = ws; ws += 98304;
    float* h1t1 = ws; ws += 98304;
    float* h2   = ws; ws += 98304;
    float* P    = ws; ws += SPLIT * FEA * NS * DIM;   // reused: pA -> pC -> pD
    float* pB   = ws; ws += SPLIT * FEA * NS * DIM;   // persists from E1 to final

    mm192x8<<<64, 192, 0, stream>>>(x, s1, xs1);          // xs1 = x @ s1

    // E1: one pass over s2t, two A-weighted outputs: (x,t0) -> h1 pre-LN, (x,t2) -> final term
    epass_kernel<true><<<SPLIT * FEA, TPB, 0, stream>>>(s2t, x, t0, t2, P, pB);
    reduce_ln_h1<<<16, 512, 0, stream>>>(P, h1);          // h1 = LN(sum P), natural layout

    mm192x8<<<64, 192, 0, stream>>>(h1, t1, h1t1);        // h1t1 = h1 @ t1

    // E2: pass over t2s with h1 (natural layout), A = s0
    epass_kernel<false><<<SPLIT * FEA, TPB, 0, stream>>>(t2s, h1, s0, nullptr, P, nullptr);
    reduce_ln_h2<<<16, 512, 0, stream>>>(P, xs1, h2);     // h2 = LN(0.5*(xs1 + sum P))

    // E3: pass over s2t with h2 (natural layout), A = t0
    epass_kernel<false><<<SPLIT * FEA, TPB, 0, stream>>>(s2t, h2, t0, nullptr, P, nullptr);

    // out = LN((pB + h1@t1 + pD)/3)
    final_ln<<<16, 512, 0, stream>>>(pB, P, h1t1, out);
}

// Round 2
// 496.504 us; speedup vs baseline: 1.0227x; 1.0227x over previous
//
#include <hip/hip_runtime.h>

// Problem dims
constexpr int NS   = 16;    // batch
constexpr int DIM  = 32;    // in_dim == out_dim
constexpr int FEA  = 192;   // in_f == out_f
constexpr int ELEMS = DIM * FEA;   // 6144 per sample

// epass tiling
constexpr int SPLIT   = 4;              // f-splits per o
constexpr int FPB     = FEA / SPLIT;    // 48 f per block
constexpr int FCHUNK  = 16;             // f per LDS stage
constexpr int NCHUNKS = FPB / FCHUNK;   // 3
constexpr int ROWPAD  = 20;             // 16 floats (n) + 4 pad
constexpr int TPB     = 256;            // epass threads per block: tid = i*8 + dq
constexpr int FSTRIDE = FEA * DIM;      // advance one f in W (6144 floats)
constexpr int PREF    = 8;              // W rolling prefetch depth (pow2, divides FCHUNK)
constexpr int REDPAD  = 68;             // reduction row stride (64 + 4 pad)
constexpr int SITER   = (FCHUNK * DIM * NS / 4) / TPB;  // 8 float4 stages/thread

typedef float vfloat4 __attribute__((ext_vector_type(4)));

// Non-temporal float4 load: W is read-once -> do not allocate in L2/L3.
// This stops the 151MB/epass W stream from thrashing X out of the caches.
__device__ __forceinline__ float4 ntload4(const float* p) {
    vfloat4 v = __builtin_nontemporal_load((const vfloat4*)p);
    return make_float4(v.x, v.y, v.z, v.w);
}

__device__ __forceinline__ void fma4(float4& a, float x, const float4& t) {
    a.x = fmaf(x, t.x, a.x);
    a.y = fmaf(x, t.y, a.y);
    a.z = fmaf(x, t.z, a.z);
    a.w = fmaf(x, t.w, a.w);
}

// One FCHUNK of the inner loop. t[PREF]: rolling 8-deep W prefetch (nt loads).
// LAST suppresses the final PREF loads (would run past W's end).
// Each thread: its own (i, dq), ALL 16 n -> acc[16] float4 (n major, 4 d comps).
template <bool DUAL, bool LAST>
__device__ __forceinline__ void chunk_compute(
    const float* __restrict__ smem, const float* __restrict__ ac0,
    const float* __restrict__ ac1, int i,
    const float*& wp, float4 (&t)[PREF],
    float4* __restrict__ accA, float4* __restrict__ accB)
{
#pragma unroll
    for (int fl = 0; fl < FCHUNK; ++fl) {
        float4 cur = t[fl & (PREF - 1)];
        if (!LAST || fl < FCHUNK - PREF) {       // compile-time after unroll
            t[fl & (PREF - 1)] = ntload4(wp);
            wp += FSTRIDE;
        }
        const float a1 = ac0[fl];
        float4 ta = make_float4(cur.x * a1, cur.y * a1, cur.z * a1, cur.w * a1);
        float4 tb;
        if (DUAL) {
            const float a2 = ac1[fl];
            tb = make_float4(cur.x * a2, cur.y * a2, cur.z * a2, cur.w * a2);
        }
        const float* xr = smem + (fl * DIM + i) * ROWPAD;
#pragma unroll
        for (int g = 0; g < 4; ++g) {            // 4 n-groups of 4
            float4 xv = *(const float4*)(xr + g * 4);
            fma4(accA[g * 4 + 0], xv.x, ta);
            fma4(accA[g * 4 + 1], xv.y, ta);
            fma4(accA[g * 4 + 2], xv.z, ta);
            fma4(accA[g * 4 + 3], xv.w, ta);
            if (DUAL) {
                fma4(accB[g * 4 + 0], xv.x, tb);
                fma4(accB[g * 4 + 1], xv.y, tb);
                fma4(accB[g * 4 + 2], xv.z, tb);
                fma4(accB[g * 4 + 3], xv.w, tb);
            }
        }
    }
}

// Weighted contraction:
//   y[n, D, O] = sum_{I=0..31, F} X[n,I,F] * W[I][F][O][D] * A[F][O]
// W layout: [32][192][192][32] (D contiguous)
// X layout: NATURAL [n][I][F] — the stager transposes into LDS [F][I][n].
// Output partials: out[s][O][n*32+D]  (512 floats per (s,O))
// Thread map: tid = i*8 + dq. Each thread: all 16 n x 4 d (dq quad).
// Per wave W load: 8 i x 128B = 1KB fully distinct (no duplicate lanes).
template <bool DUAL>
__global__ __launch_bounds__(TPB) void epass_kernel(
    const float* __restrict__ W, const float* __restrict__ X,
    const float* __restrict__ A1, const float* __restrict__ A2,
    float* __restrict__ outA, float* __restrict__ outB)
{
    __shared__ float smem[FCHUNK * DIM * ROWPAD];  // 10240 floats; reused for reduce
    __shared__ float acol[2][FPB];

    const int tid = threadIdx.x;
    const int o   = blockIdx.x >> 2;          // output O index
    const int s   = blockIdx.x & (SPLIT - 1); // f-split
    const int dq  = tid & 7;                  // D quad (0..7)
    const int i   = tid >> 3;                 // contraction I (0..31)
    const int fBase = s * FPB;

    if (tid < FPB) {
        acol[0][tid] = A1[(fBase + tid) * FEA + o];
        if (DUAL) acol[1][tid] = A2[(fBase + tid) * FEA + o];
    }

    float4 accA[16];
    float4 accB[16];
#pragma unroll
    for (int n = 0; n < 16; ++n) {
        accA[n] = make_float4(0.f, 0.f, 0.f, 0.f);
        if (DUAL) accB[n] = make_float4(0.f, 0.f, 0.f, 0.f);
    }

    const float* wp = W + (size_t)(((i * FEA + fBase) * FEA + o) * DIM + dq * 4);
    float4 t[PREF];
#pragma unroll
    for (int k = 0; k < PREF; ++k) {          // preload fs = 0..7 (nt)
        t[k] = ntload4(wp);
        wp += FSTRIDE;
    }

    for (int c = 0; c < NCHUNKS; ++c) {
        __syncthreads();
        // Stage x chunk from NATURAL layout: 16 f x 32 i x 16 n
#pragma unroll
        for (int r = 0; r < SITER; ++r) {
            int q  = r * TPB + tid;             // 2048 float4 total
            int nn = q >> 7;                    // 0..15
            int ii = (q >> 2) & 31;             // 0..31
            int fq = q & 3;                     // f quad within chunk
            float4 v = *(const float4*)(X + (size_t)(nn * DIM + ii) * FEA
                                          + fBase + c * FCHUNK + fq * 4);
            smem[((fq * 4 + 0) * DIM + ii) * ROWPAD + nn] = v.x;
            smem[((fq * 4 + 1) * DIM + ii) * ROWPAD + nn] = v.y;
            smem[((fq * 4 + 2) * DIM + ii) * ROWPAD + nn] = v.z;
            smem[((fq * 4 + 3) * DIM + ii) * ROWPAD + nn] = v.w;
        }
        __syncthreads();

        const float* ac0 = &acol[0][c * FCHUNK];
        const float* ac1 = &acol[1][c * FCHUNK];
        if (c < NCHUNKS - 1)
            chunk_compute<DUAL, false>(smem, ac0, ac1, i, wp, t, accA, accB);
        else
            chunk_compute<DUAL, true>(smem, ac0, ac1, i, wp, t, accA, accB);
    }

    // Reduce over i. Step 1: fold i_local bit2 (lane bit 5) via shfl.
#pragma unroll
    for (int n = 0; n < 16; ++n) {
        accA[n].x += __shfl_xor(accA[n].x, 32);
        accA[n].y += __shfl_xor(accA[n].y, 32);
        accA[n].z += __shfl_xor(accA[n].z, 32);
        accA[n].w += __shfl_xor(accA[n].w, 32);
        if (DUAL) {
            accB[n].x += __shfl_xor(accB[n].x, 32);
            accB[n].y += __shfl_xor(accB[n].y, 32);
            accB[n].z += __shfl_xor(accB[n].z, 32);
            accB[n].w += __shfl_xor(accB[n].w, 32);
        }
    }

    // Step 2: 16 partial rows (4 waves x 4 i-pairs) x 8 dq -> LDS, then sum.
    const int lane = tid & 63;
    const int wv   = tid >> 6;                               // 0..3
    const int row  = (wv * 4 + ((lane >> 3) & 3)) * 8 + (lane & 7);  // 0..127
    float* red = smem;                                       // reuse staging LDS

    __syncthreads();
    if (!(lane & 32)) {
#pragma unroll
        for (int n = 0; n < 16; ++n)
            *(float4*)&red[row * REDPAD + n * 4] = accA[n];
    }
    __syncthreads();
#pragma unroll
    for (int h = 0; h < 2; ++h) {
        const int e = h * TPB + tid;           // 512 outputs, 2 per thread
        const int n = e >> 5, d = e & 31;
        float v = 0.f;
#pragma unroll
        for (int w2 = 0; w2 < 16; ++w2)
            v += red[(w2 * 8 + (d >> 2)) * REDPAD + n * 4 + (d & 3)];
        outA[(size_t)(s * FEA + o) * (NS * DIM) + e] = v;
    }
    if (DUAL) {
        __syncthreads();
        if (!(lane & 32)) {
#pragma unroll
            for (int n = 0; n < 16; ++n)
                *(float4*)&red[row * REDPAD + n * 4] = accB[n];
        }
        __syncthreads();
#pragma unroll
        for (int h = 0; h < 2; ++h) {
            const int e = h * TPB + tid;
            const int n = e >> 5, d = e & 31;
            float v = 0.f;
#pragma unroll
            for (int w2 = 0; w2 < 16; ++w2)
                v += red[(w2 * 8 + (d >> 2)) * REDPAD + n * 4 + (d & 3)];
            outB[(size_t)(s * FEA + o) * (NS * DIM) + e] = v;
        }
    }
}

// ---- LN helpers (512-thread blocks) --------------------------------------

__device__ __forceinline__ float2 ln_stats_512(float s1, float s2, int tid, float* red) {
#pragma unroll
    for (int m = 1; m < 64; m <<= 1) {
        s1 += __shfl_xor(s1, m);
        s2 += __shfl_xor(s2, m);
    }
    if ((tid & 63) == 0) {
        red[(tid >> 6) * 2]     = s1;
        red[(tid >> 6) * 2 + 1] = s2;
    }
    __syncthreads();
    float a = 0.f, b = 0.f;
#pragma unroll
    for (int ww = 0; ww < 8; ++ww) { a += red[ww * 2]; b += red[ww * 2 + 1]; }
    float mean = a * (1.0f / ELEMS);
    float var  = b * (1.0f / ELEMS) - mean * mean;
    return make_float2(mean, rsqrtf(var + 1e-5f));
}

// h1 = LN(sum_s P). P layout [s][o][n*32+d]; output natural [n][d][o].
__global__ __launch_bounds__(512) void reduce_ln_h1(
    const float* __restrict__ p, float* __restrict__ h1)
{
    __shared__ float vals[FEA * 33];   // [o][d] padded
    __shared__ float red[16];
    const int n = blockIdx.x, tid = threadIdx.x;
    float s1 = 0.f, s2 = 0.f;
    for (int e = tid; e < ELEMS; e += 512) {      // d fast -> coalesced P reads
        int d = e & 31, o = e >> 5;
        float v = 0.f;
#pragma unroll
        for (int sp = 0; sp < SPLIT; ++sp)
            v += p[(size_t)(sp * FEA + o) * (NS * DIM) + n * DIM + d];
        vals[o * 33 + d] = v; s1 += v; s2 += v * v;
    }
    float2 mr = ln_stats_512(s1, s2, tid, red);
    for (int e = tid; e < ELEMS; e += 512) {      // o fast -> coalesced h1 writes
        int o = e % FEA, d = e / FEA;
        h1[(size_t)n * ELEMS + e] = (vals[o * 33 + d] - mr.x) * mr.y;
    }
}

// h2 = LN(0.5*(xs1 + sum_s P)); output natural [n][e][f].
__global__ __launch_bounds__(512) void reduce_ln_h2(
    const float* __restrict__ p, const float* __restrict__ xs1, float* __restrict__ h2)
{
    __shared__ float vals[FEA * 33];
    __shared__ float red[16];
    const int n = blockIdx.x, tid = threadIdx.x;
    for (int e = tid; e < ELEMS; e += 512) {
        int d = e & 31, o = e >> 5;
        float v = 0.f;
#pragma unroll
        for (int sp = 0; sp < SPLIT; ++sp)
            v += p[(size_t)(sp * FEA + o) * (NS * DIM) + n * DIM + d];
        vals[o * 33 + d] = v;
    }
    __syncthreads();
    float s1 = 0.f, s2 = 0.f;
    for (int e = tid; e < ELEMS; e += 512) {      // natural order for xs1
        int o = e % FEA, d = e / FEA;
        float v = 0.5f * (vals[o * 33 + d] + xs1[(size_t)n * ELEMS + e]);
        vals[o * 33 + d] = v; s1 += v; s2 += v * v;
    }
    float2 mr = ln_stats_512(s1, s2, tid, red);
    for (int e = tid; e < ELEMS; e += 512) {
        int o = e % FEA, d = e / FEA;
        h2[(size_t)n * ELEMS + e] = (vals[o * 33 + d] - mr.x) * mr.y;
    }
}

// out = LN((sum_s pB + sum_s pD + h1t1)/3); output natural [n][d][o].
__global__ __launch_bounds__(512) void final_ln(
    const float* __restrict__ pB, const float* __restrict__ pD,
    const float* __restrict__ h1t1, float* __restrict__ out)
{
    __shared__ float vals[FEA * 33];
    __shared__ float red[16];
    const int n = blockIdx.x, tid = threadIdx.x;
    for (int e = tid; e < ELEMS; e += 512) {
        int d = e & 31, o = e >> 5;
        float v = 0.f;
#pragma unroll
        for (int sp = 0; sp < SPLIT; ++sp) {
            v += pB[(size_t)(sp * FEA + o) * (NS * DIM) + n * DIM + d];
            v += pD[(size_t)(sp * FEA + o) * (NS * DIM) + n * DIM + d];
        }
        vals[o * 33 + d] = v;
    }
    __syncthreads();
    float s1 = 0.f, s2 = 0.f;
    for (int e = tid; e < ELEMS; e += 512) {
        int o = e % FEA, d = e / FEA;
        float v = (vals[o * 33 + d] + h1t1[(size_t)n * ELEMS + e]) * (1.0f / 3.0f);
        vals[o * 33 + d] = v; s1 += v; s2 += v * v;
    }
    float2 mr = ln_stats_512(s1, s2, tid, red);
    for (int e = tid; e < ELEMS; e += 512) {
        int o = e % FEA, d = e / FEA;
        out[(size_t)n * ELEMS + e] = (vals[o * 33 + d] - mr.x) * mr.y;
    }
}

// Y[r][j] = sum_f X[r][f] * M[f][j], 8 rows per block, 192 cols
__global__ __launch_bounds__(192) void mm192x8(
    const float* __restrict__ X, const float* __restrict__ M, float* __restrict__ Y)
{
    __shared__ float rows[8][192];
    const int rb = blockIdx.x * 8;
    const int j  = threadIdx.x;
#pragma unroll
    for (int k = 0; k < 8; ++k) rows[k][j] = X[(rb + k) * 192 + j];
    __syncthreads();
    float acc[8] = {0.f, 0.f, 0.f, 0.f, 0.f, 0.f, 0.f, 0.f};
    for (int f = 0; f < 192; ++f) {
        float m = M[f * 192 + j];
#pragma unroll
        for (int k = 0; k < 8; ++k) acc[k] = fmaf(rows[k][f], m, acc[k]);
    }
#pragma unroll
    for (int k = 0; k < 8; ++k) Y[(rb + k) * 192 + j] = acc[k];
}

extern "C" void kernel_launch(void* const* d_in, const int* in_sizes, int n_in,
                              void* d_out, int out_size, void* d_ws, size_t ws_size,
                              hipStream_t stream) {
    (void)in_sizes; (void)n_in; (void)out_size; (void)ws_size;
    const float* x   = (const float*)d_in[0];
    const float* s2t = (const float*)d_in[1];
    const float* t2s = (const float*)d_in[2];
    const float* s0  = (const float*)d_in[3];
    const float* s1  = (const float*)d_in[4];
    /* s2 = d_in[5] unused by the 4-layer schedule */
    const float* t0  = (const float*)d_in[6];
    const float* t1  = (const float*)d_in[7];
    const float* t2  = (const float*)d_in[8];
    float* out = (float*)d_out;

    float* ws = (float*)d_ws;
    float* xs1  = ws; ws += 98304;
    float* h1   = ws; ws += 98304;
    float* h1t1 = ws; ws += 98304;
    float* h2   = ws; ws += 98304;
    float* P    = ws; ws += SPLIT * FEA * NS * DIM;   // reused: pA -> pC -> pD
    float* pB   = ws; ws += SPLIT * FEA * NS * DIM;   // persists from E1 to final

    mm192x8<<<64, 192, 0, stream>>>(x, s1, xs1);          // xs1 = x @ s1

    // E1: one pass over s2t, two A-weighted outputs: (x,t0) -> h1 pre-LN, (x,t2) -> final term
    epass_kernel<true><<<SPLIT * FEA, TPB, 0, stream>>>(s2t, x, t0, t2, P, pB);
    reduce_ln_h1<<<16, 512, 0, stream>>>(P, h1);          // h1 = LN(sum P), natural layout

    mm192x8<<<64, 192, 0, stream>>>(h1, t1, h1t1);        // h1t1 = h1 @ t1

    // E2: pass over t2s with h1 (natural layout), A = s0
    epass_kernel<false><<<SPLIT * FEA, TPB, 0, stream>>>(t2s, h1, s0, nullptr, P, nullptr);
    reduce_ln_h2<<<16, 512, 0, stream>>>(P, xs1, h2);     // h2 = LN(0.5*(xs1 + sum P))

    // E3: pass over s2t with h2 (natural layout), A = t0
    epass_kernel<false><<<SPLIT * FEA, TPB, 0, stream>>>(s2t, h2, t0, nullptr, P, nullptr);

    // out = LN((pB + h1@t1 + pD)/3)
    final_ln<<<16, 512, 0, stream>>>(pB, P, h1t1, out);
}

// Round 3
// 472.253 us; speedup vs baseline: 1.0752x; 1.0514x over previous
//
#include <hip/hip_runtime.h>

// Problem dims
constexpr int NS   = 16;    // batch
constexpr int DIM  = 32;    // in_dim == out_dim
constexpr int FEA  = 192;   // in_f == out_f
constexpr int ELEMS = DIM * FEA;   // 6144 per sample

// epass decomposition: block = o-range(8) x i-slab(4, 1 per wave) x f-range(48)
constexpr int ORANGE  = 8;              // o per block
constexpr int OSPL    = FEA / ORANGE;   // 24 o-splits
constexpr int FPB     = 48;             // f per block
constexpr int RS      = 32;             // reduction splits: 8 i-slabs x 4 f-splits
constexpr int TPB     = 256;
constexpr int FSTRIDE = FEA * DIM;      // one f step in W (6144 floats = 24 KB)
constexpr int PSTRIDE = NS * DIM;       // 512 floats per (r,o) row in P

typedef float vfloat4 __attribute__((ext_vector_type(4)));

// Non-temporal float4 load: W is read-once -> don't thrash L2/LLC.
__device__ __forceinline__ float4 ntload4(const float* p) {
    vfloat4 v = __builtin_nontemporal_load((const vfloat4*)p);
    return make_float4(v.x, v.y, v.z, v.w);
}

__device__ __forceinline__ void fma4(float4& a, float x, const float4& t) {
    a.x = fmaf(x, t.x, a.x);
    a.y = fmaf(x, t.y, a.y);
    a.z = fmaf(x, t.z, a.z);
    a.w = fmaf(x, t.w, a.w);
}

// One f-step. slot: named rolling-prefetch register (compile-time slot; no
// runtime-indexed float4 arrays -> stays in VGPRs). LOAD=false for the tail.
template <bool DUAL, bool LOAD>
__device__ __forceinline__ void step(
    float4& slot, int fl, const float* __restrict__ xrow,
    const float* __restrict__ ac, int ol,
    const float*& wp, float4* __restrict__ accA, float4* __restrict__ accB)
{
    float4 cur = slot;
    if (LOAD) { slot = ntload4(wp); wp += FSTRIDE; }
    const float a1 = ac[fl * ORANGE + ol];
    float4 ta = make_float4(cur.x * a1, cur.y * a1, cur.z * a1, cur.w * a1);
    float4 tb;
    if (DUAL) {
        const float a2 = ac[FPB * ORANGE + fl * ORANGE + ol];
        tb = make_float4(cur.x * a2, cur.y * a2, cur.z * a2, cur.w * a2);
    }
    const float* xr = xrow + fl * NS;      // 16 n values for (i_wave, f)
#pragma unroll
    for (int g = 0; g < 4; ++g) {
        float4 xv = *(const float4*)(xr + g * 4);   // broadcast across lanes
        fma4(accA[g * 4 + 0], xv.x, ta);
        fma4(accA[g * 4 + 1], xv.y, ta);
        fma4(accA[g * 4 + 2], xv.z, ta);
        fma4(accA[g * 4 + 3], xv.w, ta);
        if (DUAL) {
            fma4(accB[g * 4 + 0], xv.x, tb);
            fma4(accB[g * 4 + 1], xv.y, tb);
            fma4(accB[g * 4 + 2], xv.z, tb);
            fma4(accB[g * 4 + 3], xv.w, tb);
        }
    }
}

// Cross-wave i-reduction (4 partials) + store. Dense lane-consecutive float4
// LDS layout -> conflict-free. red needs 8192 floats.
__device__ __forceinline__ void wave_reduce_store(
    float4* __restrict__ acc, float* __restrict__ red, int wv, int lane,
    float* __restrict__ out, int r, int oBase, int ol, int dq)
{
    __syncthreads();
    if (wv >= 2) {
        float* d = red + (wv - 2) * 4096;
#pragma unroll
        for (int n = 0; n < 16; ++n)
            *(float4*)(d + (n * 64 + lane) * 4) = acc[n];
    }
    __syncthreads();
    if (wv < 2) {
        const float* sp = red + wv * 4096;
#pragma unroll
        for (int n = 0; n < 16; ++n) {
            float4 v = *(const float4*)(sp + (n * 64 + lane) * 4);
            acc[n].x += v.x; acc[n].y += v.y; acc[n].z += v.z; acc[n].w += v.w;
        }
    }
    __syncthreads();
    if (wv == 1) {
#pragma unroll
        for (int n = 0; n < 16; ++n)
            *(float4*)(red + (n * 64 + lane) * 4) = acc[n];
    }
    __syncthreads();
    if (wv == 0) {
        float* po = out + (size_t)(r * FEA + oBase + ol) * PSTRIDE + dq * 4;
#pragma unroll
        for (int n = 0; n < 16; ++n) {
            float4 v = *(const float4*)(red + (n * 64 + lane) * 4);
            float4 w = make_float4(acc[n].x + v.x, acc[n].y + v.y,
                                   acc[n].z + v.z, acc[n].w + v.w);
            *(float4*)(po + n * DIM) = w;
        }
    }
}

// Weighted contraction:
//   y[n, D, O] = sum_{I,F} X[n,I,F] * W[I][F][O][D] * A[F][O]
// Block: o-range 8 (lane hi bits) x 4 i (one per wave) x 48 f.
// Lane = ol*8 + dq; wave W load = W[i][f][o0:o0+8][:] = 1 KB CONTIGUOUS,
// lane l's float4 sits at byte l*16 of it (load map == compute map).
// Output partials: out[r][O][n*32+D], r = i-slab*4 + f-split (32 partials).
template <bool DUAL>
__global__ __launch_bounds__(TPB) void epass_kernel(
    const float* __restrict__ W, const float* __restrict__ X,
    const float* __restrict__ A1, const float* __restrict__ A2,
    float* __restrict__ outA, float* __restrict__ outB)
{
    __shared__ float smem[8192];           // 32 KB: xs+ac during compute; red after
    float* xs = smem;                      // [il 4][f 48][n 16] = 3072
    float* ac = smem + 3072;               // [2][48][8] = 768

    const int tid  = threadIdx.x;
    const int bid  = blockIdx.x;
    const int r    = bid & 31;             // reduction split
    const int oS   = bid >> 5;             // 0..23
    const int iBase = (r >> 2) * 4;
    const int fBase = (r & 3) * FPB;
    const int oBase = oS * ORANGE;
    const int wv   = tid >> 6;
    const int lane = tid & 63;
    const int ol   = lane >> 3;            // o_local 0..7
    const int dq   = lane & 7;             // d quad 0..7
    const int i    = iBase + wv;           // this wave's contraction i

    // W rolling prefetch: preload f = 0..3 (issued before staging for overlap)
    const float* wp = W + ((size_t)(i * FEA + fBase) * FEA + oBase) * DIM + lane * 4;
    float4 t0 = ntload4(wp); wp += FSTRIDE;
    float4 t1 = ntload4(wp); wp += FSTRIDE;
    float4 t2 = ntload4(wp); wp += FSTRIDE;
    float4 t3 = ntload4(wp); wp += FSTRIDE;

    // Stage A columns: ac[0][f][ol], ac[1][f][ol]
    for (int t = tid; t < FPB * ORANGE; t += TPB) {
        int f = t >> 3, o = t & 7;
        ac[t] = A1[(fBase + f) * FEA + oBase + o];
        if (DUAL) ac[FPB * ORANGE + t] = A2[(fBase + f) * FEA + oBase + o];
    }

    // Stage ALL X for this block up front: xs[il][f][n], 3072 floats, 768 float4
#pragma unroll
    for (int it = 0; it < 3; ++it) {
        int q  = it * TPB + tid;           // 0..767
        int fq = q % 12;                   // f quad (fastest -> coalesced)
        int rem = q / 12;
        int n  = rem & 15;
        int il = rem >> 4;
        float4 v = *(const float4*)(X + (size_t)(n * DIM + iBase + il) * FEA
                                      + fBase + fq * 4);
        float* dst = xs + (il * FPB + fq * 4) * NS + n;
        dst[0]      = v.x;
        dst[NS]     = v.y;
        dst[2 * NS] = v.z;
        dst[3 * NS] = v.w;
    }

    float4 accA[16], accB[16];
#pragma unroll
    for (int n = 0; n < 16; ++n) {
        accA[n] = make_float4(0.f, 0.f, 0.f, 0.f);
        if (DUAL) accB[n] = make_float4(0.f, 0.f, 0.f, 0.f);
    }

    __syncthreads();                       // xs + ac ready; no more barriers in loop

    const float* xrow = xs + wv * (FPB * NS);
    for (int f4 = 0; f4 < 11; ++f4) {      // f = 0..43, always prefetch f+4
        const int fl = f4 * 4;
        step<DUAL, true>(t0, fl + 0, xrow, ac, ol, wp, accA, accB);
        step<DUAL, true>(t1, fl + 1, xrow, ac, ol, wp, accA, accB);
        step<DUAL, true>(t2, fl + 2, xrow, ac, ol, wp, accA, accB);
        step<DUAL, true>(t3, fl + 3, xrow, ac, ol, wp, accA, accB);
    }
    step<DUAL, false>(t0, 44, xrow, ac, ol, wp, accA, accB);
    step<DUAL, false>(t1, 45, xrow, ac, ol, wp, accA, accB);
    step<DUAL, false>(t2, 46, xrow, ac, ol, wp, accA, accB);
    step<DUAL, false>(t3, 47, xrow, ac, ol, wp, accA, accB);

    wave_reduce_store(accA, smem, wv, lane, outA, r, oBase, ol, dq);
    if (DUAL)
        wave_reduce_store(accB, smem, wv, lane, outB, r, oBase, ol, dq);
}

// ---- LN helpers (512-thread blocks) --------------------------------------

__device__ __forceinline__ void acc4(float4& a, const float4 b) {
    a.x += b.x; a.y += b.y; a.z += b.z; a.w += b.w;
}

__device__ __forceinline__ float2 ln_stats_512(float s1, float s2, int tid, float* red) {
#pragma unroll
    for (int m = 1; m < 64; m <<= 1) {
        s1 += __shfl_xor(s1, m);
        s2 += __shfl_xor(s2, m);
    }
    if ((tid & 63) == 0) {
        red[(tid >> 6) * 2]     = s1;
        red[(tid >> 6) * 2 + 1] = s2;
    }
    __syncthreads();
    float a = 0.f, b = 0.f;
#pragma unroll
    for (int ww = 0; ww < 8; ++ww) { a += red[ww * 2]; b += red[ww * 2 + 1]; }
    float mean = a * (1.0f / ELEMS);
    float var  = b * (1.0f / ELEMS) - mean * mean;
    return make_float2(mean, rsqrtf(var + 1e-5f));
}

// Sum RS partials of P at (n, o, d..d+3) -> float4
__device__ __forceinline__ float4 sumP(const float* __restrict__ p, int n, int o, int d) {
    const float* pp = p + (size_t)o * PSTRIDE + n * DIM + d;
    float4 a = make_float4(0.f, 0.f, 0.f, 0.f);
#pragma unroll
    for (int sp = 0; sp < RS; ++sp)
        acc4(a, *(const float4*)(pp + (size_t)sp * FEA * PSTRIDE));
    return a;
}

// h1 = LN(sum_r P). P layout [r][o][n*32+d]; output natural [n][d][o].
__global__ __launch_bounds__(512) void reduce_ln_h1(
    const float* __restrict__ p, float* __restrict__ h1)
{
    __shared__ float vals[FEA * 33];   // [o][d] padded
    __shared__ float red[16];
    const int n = blockIdx.x, tid = threadIdx.x;
    float s1 = 0.f, s2 = 0.f;
    for (int b = tid * 4; b < ELEMS; b += 2048) {
        int d = b & 31, o = b >> 5;
        float4 a = sumP(p, n, o, d);
        vals[o * 33 + d]     = a.x;
        vals[o * 33 + d + 1] = a.y;
        vals[o * 33 + d + 2] = a.z;
        vals[o * 33 + d + 3] = a.w;
        s1 += a.x + a.y + a.z + a.w;
        s2 += a.x * a.x + a.y * a.y + a.z * a.z + a.w * a.w;
    }
    float2 mr = ln_stats_512(s1, s2, tid, red);
    for (int e = tid; e < ELEMS; e += 512) {      // o fast -> coalesced h1 writes
        int o = e % FEA, d = e / FEA;
        h1[(size_t)n * ELEMS + e] = (vals[o * 33 + d] - mr.x) * mr.y;
    }
}

// h2 = LN(0.5*(xs1 + sum_r P)); output natural [n][e][f].
__global__ __launch_bounds__(512) void reduce_ln_h2(
    const float* __restrict__ p, const float* __restrict__ xs1, float* __restrict__ h2)
{
    __shared__ float vals[FEA * 33];
    __shared__ float red[16];
    const int n = blockIdx.x, tid = threadIdx.x;
    for (int b = tid * 4; b < ELEMS; b += 2048) {
        int d = b & 31, o = b >> 5;
        float4 a = sumP(p, n, o, d);
        vals[o * 33 + d]     = a.x;
        vals[o * 33 + d + 1] = a.y;
        vals[o * 33 + d + 2] = a.z;
        vals[o * 33 + d + 3] = a.w;
    }
    __syncthreads();
    float s1 = 0.f, s2 = 0.f;
    for (int e = tid; e < ELEMS; e += 512) {      // natural order for xs1
        int o = e % FEA, d = e / FEA;
        float v = 0.5f * (vals[o * 33 + d] + xs1[(size_t)n * ELEMS + e]);
        vals[o * 33 + d] = v; s1 += v; s2 += v * v;
    }
    float2 mr = ln_stats_512(s1, s2, tid, red);
    for (int e = tid; e < ELEMS; e += 512) {
        int o = e % FEA, d = e / FEA;
        h2[(size_t)n * ELEMS + e] = (vals[o * 33 + d] - mr.x) * mr.y;
    }
}

// out = LN((sum_r pB + sum_r pD + h1t1)/3); output natural [n][d][o].
__global__ __launch_bounds__(512) void final_ln(
    const float* __restrict__ pB, const float* __restrict__ pD,
    const float* __restrict__ h1t1, float* __restrict__ out)
{
    __shared__ float vals[FEA * 33];
    __shared__ float red[16];
    const int n = blockIdx.x, tid = threadIdx.x;
    for (int b = tid * 4; b < ELEMS; b += 2048) {
        int d = b & 31, o = b >> 5;
        float4 a = sumP(pB, n, o, d);
        float4 c = sumP(pD, n, o, d);
        acc4(a, c);
        vals[o * 33 + d]     = a.x;
        vals[o * 33 + d + 1] = a.y;
        vals[o * 33 + d + 2] = a.z;
        vals[o * 33 + d + 3] = a.w;
    }
    __syncthreads();
    float s1 = 0.f, s2 = 0.f;
    for (int e = tid; e < ELEMS; e += 512) {
        int o = e % FEA, d = e / FEA;
        float v = (vals[o * 33 + d] + h1t1[(size_t)n * ELEMS + e]) * (1.0f / 3.0f);
        vals[o * 33 + d] = v; s1 += v; s2 += v * v;
    }
    float2 mr = ln_stats_512(s1, s2, tid, red);
    for (int e = tid; e < ELEMS; e += 512) {
        int o = e % FEA, d = e / FEA;
        out[(size_t)n * ELEMS + e] = (vals[o * 33 + d] - mr.x) * mr.y;
    }
}

// Y[r][j] = sum_f X[r][f] * M[f][j], 8 rows per block, 192 cols
__global__ __launch_bounds__(192) void mm192x8(
    const float* __restrict__ X, const float* __restrict__ M, float* __restrict__ Y)
{
    __shared__ float rows[8][192];
    const int rb = blockIdx.x * 8;
    const int j  = threadIdx.x;
#pragma unroll
    for (int k = 0; k < 8; ++k) rows[k][j] = X[(rb + k) * 192 + j];
    __syncthreads();
    float acc[8] = {0.f, 0.f, 0.f, 0.f, 0.f, 0.f, 0.f, 0.f};
    for (int f = 0; f < 192; ++f) {
        float m = M[f * 192 + j];
#pragma unroll
        for (int k = 0; k < 8; ++k) acc[k] = fmaf(rows[k][f], m, acc[k]);
    }
#pragma unroll
    for (int k = 0; k < 8; ++k) Y[(rb + k) * 192 + j] = acc[k];
}

extern "C" void kernel_launch(void* const* d_in, const int* in_sizes, int n_in,
                              void* d_out, int out_size, void* d_ws, size_t ws_size,
                              hipStream_t stream) {
    (void)in_sizes; (void)n_in; (void)out_size; (void)ws_size;
    const float* x   = (const float*)d_in[0];
    const float* s2t = (const float*)d_in[1];
    const float* t2s = (const float*)d_in[2];
    const float* s0  = (const float*)d_in[3];
    const float* s1  = (const float*)d_in[4];
    /* s2 = d_in[5] unused by the 4-layer schedule */
    const float* t0  = (const float*)d_in[6];
    const float* t1  = (const float*)d_in[7];
    const float* t2  = (const float*)d_in[8];
    float* out = (float*)d_out;

    float* ws = (float*)d_ws;
    float* xs1  = ws; ws += 98304;
    float* h1   = ws; ws += 98304;
    float* h1t1 = ws; ws += 98304;
    float* h2   = ws; ws += 98304;
    float* P    = ws; ws += RS * FEA * NS * DIM;   // reused: pA -> pC -> pD
    float* pB   = ws; ws += RS * FEA * NS * DIM;   // persists from E1 to final

    mm192x8<<<64, 192, 0, stream>>>(x, s1, xs1);          // xs1 = x @ s1

    // E1: one pass over s2t, two A-weighted outputs: (x,t0) -> h1 pre-LN, (x,t2) -> final term
    epass_kernel<true><<<OSPL * RS, TPB, 0, stream>>>(s2t, x, t0, t2, P, pB);
    reduce_ln_h1<<<16, 512, 0, stream>>>(P, h1);          // h1 = LN(sum P), natural layout

    mm192x8<<<64, 192, 0, stream>>>(h1, t1, h1t1);        // h1t1 = h1 @ t1

    // E2: pass over t2s with h1 (natural layout), A = s0
    epass_kernel<false><<<OSPL * RS, TPB, 0, stream>>>(t2s, h1, s0, nullptr, P, nullptr);
    reduce_ln_h2<<<16, 512, 0, stream>>>(P, xs1, h2);     // h2 = LN(0.5*(xs1 + sum P))

    // E3: pass over s2t with h2 (natural layout), A = t0
    epass_kernel<false><<<OSPL * RS, TPB, 0, stream>>>(s2t, h2, t0, nullptr, P, nullptr);

    // out = LN((pB + h1@t1 + pD)/3)
    final_ln<<<16, 512, 0, stream>>>(pB, P, h1t1, out);
}